// Round 8
// baseline (657.382 us; speedup 1.0000x reference)
//
#include <hip/hip_runtime.h>
#include <hip/hip_bf16.h>

#define NREL 3
#define EMB 32
#define HID 64

typedef __attribute__((ext_vector_type(8))) short short8_t;
typedef __attribute__((ext_vector_type(4))) short short4_t;
typedef __attribute__((ext_vector_type(4))) float f32x4;

__device__ inline short f2bf(float v) {
  __hip_bfloat16 b = __float2bfloat16(v);
  short s;
  __builtin_memcpy(&s, &b, 2);
  return s;
}
__device__ inline float bf2f(short s) {
  __hip_bfloat16 b;
  __builtin_memcpy(&b, &s, 2);
  return __bfloat162float(b);
}
// split v into hi+lo bf16 (lo = residual); hi*B + lo*B recovers ~fp32 precision
__device__ inline void store_split(short* ph, short* pl, float4 v) {
  short4_t h, l;
  h.x = f2bf(v.x); l.x = f2bf(v.x - bf2f(h.x));
  h.y = f2bf(v.y); l.y = f2bf(v.y - bf2f(h.y));
  h.z = f2bf(v.z); l.z = f2bf(v.z - bf2f(h.z));
  h.w = f2bf(v.w); l.w = f2bf(v.w - bf2f(h.w));
  *(short4_t*)ph = h;
  *(short4_t*)pl = l;
}

// ---------------- embedding materialize: x[n][0:32] fp32 ----------------
__global__ __launch_bounds__(256) void embed_k(
    const int* __restrict__ sid, const int* __restrict__ cid, const int* __restrict__ pid,
    const float* __restrict__ se, const float* __restrict__ ce, const float* __restrict__ pe,
    float* __restrict__ x, int N) {
  int i = blockIdx.x * 256 + threadIdx.x;
  if (i >= N * 8) return;
  int n = i >> 3, cg = i & 7;
  const float4 a = *(const float4*)&se[sid[n] * EMB + cg * 4];
  const float4 b = *(const float4*)&ce[cid[n] * EMB + cg * 4];
  const float4 c = *(const float4*)&pe[pid[n] * EMB + cg * 4];
  float4 v;
  v.x = a.x + b.x + c.x; v.y = a.y + b.y + c.y;
  v.z = a.z + b.z + c.z; v.w = a.w + b.w + c.w;
  *(float4*)&x[(size_t)n * EMB + cg * 4] = v;
}

// ---- weight prep: transpose+stack+split to bf16 hi/lo, n-major [64][K] ----
__global__ __launch_bounds__(256) void wprep_k(
    const float* __restrict__ root1, const float* __restrict__ W1,
    const float* __restrict__ root2, const float* __restrict__ W2,
    short* __restrict__ w1h, short* __restrict__ w1l,
    short* __restrict__ w2h, short* __restrict__ w2l) {
  int i = blockIdx.x * 256 + threadIdx.x;
  if (i < 64 * 128) {  // layer 1: K=128
    int k = i >> 6, n = i & 63;
    float v = (k < EMB) ? root1[k * 64 + n] : W1[(k - EMB) * 64 + n];
    short h = f2bf(v);
    w1h[n * 128 + k] = h;
    w1l[n * 128 + k] = f2bf(v - bf2f(h));
  }
  int j = i - 64 * 128;
  if (j >= 0 && j < 64 * 256) {  // layer 2: K=256
    int k = j >> 6, n = j & 63;
    float v = (k < HID) ? root2[k * 64 + n] : W2[(k - HID) * 64 + n];
    short h = f2bf(v);
    w2h[n * 256 + k] = h;
    w2l[n * 256 + k] = f2bf(v - bf2f(h));
  }
}

// ================= CSR build, RELATION-MAJOR: key = rel*N + dst =================
__global__ __launch_bounds__(256) void hist_k(const int* __restrict__ dst,
                                              const int* __restrict__ et,
                                              int* __restrict__ icnt, int E, int N) {
  int e = blockIdx.x * 256 + threadIdx.x;
  if (e >= E) return;
  atomicAdd(&icnt[et[e] * N + dst[e]], 1);
}

__global__ __launch_bounds__(256) void scan1_k(const int* __restrict__ icnt,
                                               int* __restrict__ psum, int M) {
  int base = blockIdx.x * 1024 + threadIdx.x * 4;
  int s = 0;
#pragma unroll
  for (int j = 0; j < 4; j++) {
    int i = base + j;
    if (i < M) s += icnt[i];
  }
  __shared__ int tmp[256];
  tmp[threadIdx.x] = s;
  __syncthreads();
  for (int off = 128; off > 0; off >>= 1) {
    if (threadIdx.x < off) tmp[threadIdx.x] += tmp[threadIdx.x + off];
    __syncthreads();
  }
  if (threadIdx.x == 0) psum[blockIdx.x] = tmp[0];
}

__global__ __launch_bounds__(256) void scan2_k(int* __restrict__ psum, int P) {
  __shared__ int tmp[256];
  __shared__ int carry_s;
  if (threadIdx.x == 0) carry_s = 0;
  __syncthreads();
  for (int base = 0; base < P; base += 256) {
    int i = base + threadIdx.x;
    int v = (i < P) ? psum[i] : 0;
    tmp[threadIdx.x] = v;
    __syncthreads();
    for (int off = 1; off < 256; off <<= 1) {
      int u = (threadIdx.x >= off) ? tmp[threadIdx.x - off] : 0;
      __syncthreads();
      tmp[threadIdx.x] += u;
      __syncthreads();
    }
    int carry = carry_s;
    if (i < P) psum[i] = carry + tmp[threadIdx.x] - v;
    __syncthreads();
    if (threadIdx.x == 0) carry_s = carry + tmp[255];
    __syncthreads();
  }
}

__global__ __launch_bounds__(256) void scan3_k(const int* __restrict__ icnt,
                                               const int* __restrict__ psum,
                                               int* __restrict__ offs, int M) {
  int base = blockIdx.x * 1024 + threadIdx.x * 4;
  int v[4];
  int s = 0;
#pragma unroll
  for (int j = 0; j < 4; j++) {
    int i = base + j;
    v[j] = (i < M) ? icnt[i] : 0;
    s += v[j];
  }
  __shared__ int tmp[256];
  tmp[threadIdx.x] = s;
  __syncthreads();
  for (int off = 1; off < 256; off <<= 1) {
    int u = (threadIdx.x >= off) ? tmp[threadIdx.x - off] : 0;
    __syncthreads();
    tmp[threadIdx.x] += u;
    __syncthreads();
  }
  int run = psum[blockIdx.x] + tmp[threadIdx.x] - s;
#pragma unroll
  for (int j = 0; j < 4; j++) {
    int i = base + j;
    if (i < M) {
      offs[i] = run;
      run += v[j];
    }
  }
}

__global__ __launch_bounds__(256) void scatter_k(const int* __restrict__ src,
                                                 const int* __restrict__ dst,
                                                 const int* __restrict__ et,
                                                 int* __restrict__ cursor,
                                                 int* __restrict__ csr, int E, int N) {
  int e = blockIdx.x * 256 + threadIdx.x;
  if (e >= E) return;
  int p = atomicAdd(&cursor[et[e] * N + dst[e]], 1);
  csr[p] = src[e];
}

// ====== layer-1 fused: register-walk gather + split-bf16 MFMA GEMM -> h1 (fp32) ======
__global__ __launch_bounds__(256) void l1fused_k(
    const float* __restrict__ x,
    const int* __restrict__ offs, const int* __restrict__ icnt, const int* __restrict__ csr,
    const short* __restrict__ wth, const short* __restrict__ wtl,
    const float* __restrict__ bias, float* __restrict__ h1, int N) {
  __shared__ short Ah[64][88], Al[64][88], Bh[64][88], Bl[64][88];  // stride 88: 16B-aligned, 2-way banks
  const int t = threadIdx.x;
  const int tx = t & 15, ty = t >> 4;
  const int lane = t & 63, w = t >> 6;
  const int m_ = lane & 15, q = lane >> 4;
  const int n0 = blockIdx.x * 64;
  f32x4 acc[4];
#pragma unroll
  for (int i = 0; i < 4; i++) acc[i] = (f32x4){0.f, 0.f, 0.f, 0.f};

  for (int kc = 0; kc < 2; kc++) {
    __syncthreads();
    {  // stage W chunk (pre-split, n-major): thread covers 16 k's of one n-row
      int n = t >> 2, part = t & 3;
      const short8_t* gh = (const short8_t*)&wth[n * 128 + kc * 64 + part * 16];
      const short8_t* gl = (const short8_t*)&wtl[n * 128 + kc * 64 + part * 16];
      *(short8_t*)&Bh[n][part * 16] = gh[0];
      *(short8_t*)&Bh[n][part * 16 + 8] = gh[1];
      *(short8_t*)&Bl[n][part * 16] = gl[0];
      *(short8_t*)&Bl[n][part * 16 + 8] = gl[1];
    }
    const int c4 = tx * 4;
    if (kc == 0 && c4 < 32) {  // self cols: copy x
#pragma unroll
      for (int m = 0; m < 4; m++) {
        int n = n0 + ty * 4 + m;
        if (n >= N) n = N - 1;
        float4 v = *(const float4*)&x[(size_t)n * EMB + c4];
        store_split(&Ah[ty * 4 + m][c4], &Al[ty * 4 + m][c4], v);
      }
    } else {  // mean cols: register walk, 4 merged segments
      int r, cc;
      if (kc == 0) { r = 0; cc = c4 - 32; }
      else { r = 1 + (c4 >> 5); cc = c4 & 31; }
      int beg[4], len[4];
      int mx = 0;
#pragma unroll
      for (int m = 0; m < 4; m++) {
        int n = n0 + ty * 4 + m;
        if (n >= N) n = N - 1;
        int idx = r * N + n;
        beg[m] = offs[idx];
        len[m] = icnt[idx];
        mx = max(mx, len[m]);
      }
      float4 a[4] = {};
      for (int j = 0; j < mx; j++) {
        int s[4];
#pragma unroll
        for (int m = 0; m < 4; m++) s[m] = (j < len[m]) ? csr[beg[m] + j] : -1;
#pragma unroll
        for (int m = 0; m < 4; m++)
          if (s[m] >= 0) {
            float4 v = *(const float4*)&x[(size_t)s[m] * EMB + cc];
            a[m].x += v.x; a[m].y += v.y; a[m].z += v.z; a[m].w += v.w;
          }
      }
#pragma unroll
      for (int m = 0; m < 4; m++) {
        float inv = 1.f / fmaxf((float)len[m], 1.f);
        a[m].x *= inv; a[m].y *= inv; a[m].z *= inv; a[m].w *= inv;
        store_split(&Ah[ty * 4 + m][c4], &Al[ty * 4 + m][c4], a[m]);
      }
    }
    __syncthreads();
    // MFMA: wave w owns m-tile rows 16w..16w+15; 4 n-tiles; K=64 in 2 sub-steps
    short8_t ah[2], al[2];
#pragma unroll
    for (int s = 0; s < 2; s++) {
      ah[s] = *(const short8_t*)&Ah[16 * w + m_][s * 32 + q * 8];
      al[s] = *(const short8_t*)&Al[16 * w + m_][s * 32 + q * 8];
    }
#pragma unroll
    for (int tt = 0; tt < 4; tt++) {
#pragma unroll
      for (int s = 0; s < 2; s++) {
        short8_t bh = *(const short8_t*)&Bh[16 * tt + m_][s * 32 + q * 8];
        short8_t bl = *(const short8_t*)&Bl[16 * tt + m_][s * 32 + q * 8];
        acc[tt] = __builtin_amdgcn_mfma_f32_16x16x32_bf16(ah[s], bh, acc[tt], 0, 0, 0);
        acc[tt] = __builtin_amdgcn_mfma_f32_16x16x32_bf16(ah[s], bl, acc[tt], 0, 0, 0);
        acc[tt] = __builtin_amdgcn_mfma_f32_16x16x32_bf16(al[s], bh, acc[tt], 0, 0, 0);
      }
    }
  }
  // epilogue: C-layout col=lane&15, row=quad*4+reg -> h1 fp32 + relu
#pragma unroll
  for (int tt = 0; tt < 4; tt++) {
    float bia = bias[16 * tt + m_];
#pragma unroll
    for (int reg = 0; reg < 4; reg++) {
      int node = n0 + 16 * w + q * 4 + reg;
      if (node < N) h1[(size_t)node * HID + 16 * tt + m_] = fmaxf(acc[tt][reg] + bia, 0.f);
    }
  }
}

// ====== layer-2 fused: register-walk gather + split-bf16 MFMA GEMM + pooled epilogue ======
__global__ __launch_bounds__(256) void l2fused_k(
    const float* __restrict__ h1,
    const int* __restrict__ offs, const int* __restrict__ icnt, const int* __restrict__ csr,
    const short* __restrict__ wth, const short* __restrict__ wtl,
    const float* __restrict__ bias, const float* __restrict__ linW,
    const int* __restrict__ batch, float* __restrict__ gs, float* __restrict__ gc, int N) {
  __shared__ short Ah[64][88], Al[64][88], Bh[64][88], Bl[64][88];
  const int t = threadIdx.x;
  const int tx = t & 15, ty = t >> 4;
  const int lane = t & 63, w = t >> 6;
  const int m_ = lane & 15, q = lane >> 4;
  const int n0 = blockIdx.x * 64;
  f32x4 acc[4];
#pragma unroll
  for (int i = 0; i < 4; i++) acc[i] = (f32x4){0.f, 0.f, 0.f, 0.f};

  for (int kc = 0; kc < 4; kc++) {
    __syncthreads();
    {  // stage W chunk
      int n = t >> 2, part = t & 3;
      const short8_t* gh = (const short8_t*)&wth[n * 256 + kc * 64 + part * 16];
      const short8_t* gl = (const short8_t*)&wtl[n * 256 + kc * 64 + part * 16];
      *(short8_t*)&Bh[n][part * 16] = gh[0];
      *(short8_t*)&Bh[n][part * 16 + 8] = gh[1];
      *(short8_t*)&Bl[n][part * 16] = gl[0];
      *(short8_t*)&Bl[n][part * 16 + 8] = gl[1];
    }
    const int c4 = tx * 4;
    if (kc == 0) {  // self: copy h1 rows
#pragma unroll
      for (int m = 0; m < 4; m++) {
        int n = n0 + ty * 4 + m;
        if (n >= N) n = N - 1;
        float4 v = *(const float4*)&h1[(size_t)n * HID + c4];
        store_split(&Ah[ty * 4 + m][c4], &Al[ty * 4 + m][c4], v);
      }
    } else {  // relation kc-1: register walk, 4 merged segments
      int r = kc - 1;
      int beg[4], len[4];
      int mx = 0;
#pragma unroll
      for (int m = 0; m < 4; m++) {
        int n = n0 + ty * 4 + m;
        if (n >= N) n = N - 1;
        int idx = r * N + n;
        beg[m] = offs[idx];
        len[m] = icnt[idx];
        mx = max(mx, len[m]);
      }
      float4 a[4] = {};
      for (int j = 0; j < mx; j++) {
        int s[4];
#pragma unroll
        for (int m = 0; m < 4; m++) s[m] = (j < len[m]) ? csr[beg[m] + j] : -1;
#pragma unroll
        for (int m = 0; m < 4; m++)
          if (s[m] >= 0) {
            float4 v = *(const float4*)&h1[(size_t)s[m] * HID + c4];
            a[m].x += v.x; a[m].y += v.y; a[m].z += v.z; a[m].w += v.w;
          }
      }
#pragma unroll
      for (int m = 0; m < 4; m++) {
        float inv = 1.f / fmaxf((float)len[m], 1.f);
        a[m].x *= inv; a[m].y *= inv; a[m].z *= inv; a[m].w *= inv;
        store_split(&Ah[ty * 4 + m][c4], &Al[ty * 4 + m][c4], a[m]);
      }
    }
    __syncthreads();
    short8_t ah[2], al[2];
#pragma unroll
    for (int s = 0; s < 2; s++) {
      ah[s] = *(const short8_t*)&Ah[16 * w + m_][s * 32 + q * 8];
      al[s] = *(const short8_t*)&Al[16 * w + m_][s * 32 + q * 8];
    }
#pragma unroll
    for (int tt = 0; tt < 4; tt++) {
#pragma unroll
      for (int s = 0; s < 2; s++) {
        short8_t bh = *(const short8_t*)&Bh[16 * tt + m_][s * 32 + q * 8];
        short8_t bl = *(const short8_t*)&Bl[16 * tt + m_][s * 32 + q * 8];
        acc[tt] = __builtin_amdgcn_mfma_f32_16x16x32_bf16(ah[s], bh, acc[tt], 0, 0, 0);
        acc[tt] = __builtin_amdgcn_mfma_f32_16x16x32_bf16(ah[s], bl, acc[tt], 0, 0, 0);
        acc[tt] = __builtin_amdgcn_mfma_f32_16x16x32_bf16(al[s], bh, acc[tt], 0, 0, 0);
      }
    }
  }
  // pooled epilogue: bias+relu, 64->2 projection, reduce over 16 col-lanes of each quad
  float bia[4], lw0[4], lw1[4];
#pragma unroll
  for (int tt = 0; tt < 4; tt++) {
    int col = 16 * tt + m_;
    bia[tt] = bias[col];
    lw0[tt] = linW[col * 2 + 0];
    lw1[tt] = linW[col * 2 + 1];
  }
#pragma unroll
  for (int reg = 0; reg < 4; reg++) {
    int node = n0 + 16 * w + q * 4 + reg;
    float p0 = 0.f, p1 = 0.f;
#pragma unroll
    for (int tt = 0; tt < 4; tt++) {
      float v = fmaxf(acc[tt][reg] + bia[tt], 0.f);
      p0 += v * lw0[tt];
      p1 += v * lw1[tt];
    }
#pragma unroll
    for (int o = 1; o < 16; o <<= 1) {
      p0 += __shfl_xor(p0, o, 64);
      p1 += __shfl_xor(p1, o, 64);
    }
    if (m_ == 0 && node < N) {
      int g = batch[node];
      atomicAdd(&gs[g * 2 + 0], p0);
      atomicAdd(&gs[g * 2 + 1], p1);
      atomicAdd(&gc[g], 1.0f);
    }
  }
}

__global__ __launch_bounds__(256) void final_k(const float* __restrict__ gs,
                                               const float* __restrict__ gc,
                                               const float* __restrict__ linb,
                                               float* __restrict__ out, int G) {
  int i = blockIdx.x * 256 + threadIdx.x;
  if (i >= G * 2) return;
  int g = i >> 1, o = i & 1;
  out[i] = gs[i] / fmaxf(gc[g], 1.0f) + linb[o];
}

extern "C" void kernel_launch(void* const* d_in, const int* in_sizes, int n_in,
                              void* d_out, int out_size, void* d_ws, size_t ws_size,
                              hipStream_t stream) {
  const int* sid = (const int*)d_in[0];
  const int* cid = (const int*)d_in[1];
  const int* pid = (const int*)d_in[2];
  const int* ei = (const int*)d_in[3];
  const int* et = (const int*)d_in[4];
  const int* batch = (const int*)d_in[5];
  const float* se = (const float*)d_in[7];
  const float* ce = (const float*)d_in[8];
  const float* pe = (const float*)d_in[9];
  const float* W1 = (const float*)d_in[10];
  const float* root1 = (const float*)d_in[11];
  const float* b1 = (const float*)d_in[12];
  const float* W2 = (const float*)d_in[13];
  const float* root2 = (const float*)d_in[14];
  const float* b2 = (const float*)d_in[15];
  const float* linW = (const float*)d_in[16];
  const float* linb = (const float*)d_in[17];
  float* out = (float*)d_out;

  const int N = in_sizes[0];
  const int E = in_sizes[4];
  const int G = out_size / 2;
  const int* src = ei;
  const int* dst = ei + E;
  const int M = N * NREL;
  const int P = (M + 1023) / 1024;

  // ---- workspace layout (strictly budgeted) ----
  char* w = (char*)d_ws;
  float* h1 = (float*)w;   w += (size_t)N * HID * sizeof(float);
  float* x = (float*)w;    w += (size_t)N * EMB * sizeof(float);
  float* gs = (float*)w;   w += (size_t)G * 2 * sizeof(float);
  float* gc = (float*)w;   w += (size_t)G * sizeof(float);
  int* icnt = (int*)w;     w += (size_t)M * sizeof(int);
  int* offs = (int*)w;     w += (size_t)M * sizeof(int);
  int* cursor = (int*)w;   w += (size_t)M * sizeof(int);
  int* csr = (int*)w;      w += (size_t)E * sizeof(int);
  short* w1h = (short*)w;  w += (size_t)64 * 128 * sizeof(short);
  short* w1l = (short*)w;  w += (size_t)64 * 128 * sizeof(short);
  short* w2h = (short*)w;  w += (size_t)64 * 256 * sizeof(short);
  short* w2l = (short*)w;  w += (size_t)64 * 256 * sizeof(short);
  int* psum = (int*)w;     w += (size_t)P * sizeof(int);
  if ((size_t)(w - (char*)d_ws) > ws_size) return;  // fail loudly, no OOB

  hipMemsetAsync(icnt, 0, (size_t)M * sizeof(int), stream);
  hipMemsetAsync(gs, 0, (size_t)G * 3 * sizeof(float), stream);

  wprep_k<<<(64 * 128 + 64 * 256 + 255) / 256, 256, 0, stream>>>(root1, W1, root2, W2, w1h, w1l,
                                                                 w2h, w2l);
  embed_k<<<(N * 8 + 255) / 256, 256, 0, stream>>>(sid, cid, pid, se, ce, pe, x, N);
  hist_k<<<(E + 255) / 256, 256, 0, stream>>>(dst, et, icnt, E, N);
  scan1_k<<<P, 256, 0, stream>>>(icnt, psum, M);
  scan2_k<<<1, 256, 0, stream>>>(psum, P);
  scan3_k<<<P, 256, 0, stream>>>(icnt, psum, offs, M);
  hipMemcpyAsync(cursor, offs, (size_t)M * sizeof(int), hipMemcpyDeviceToDevice, stream);
  scatter_k<<<(E + 255) / 256, 256, 0, stream>>>(src, dst, et, cursor, csr, E, N);

  int blocks = (N + 63) / 64;
  l1fused_k<<<blocks, 256, 0, stream>>>(x, offs, icnt, csr, w1h, w1l, b1, h1, N);
  l2fused_k<<<blocks, 256, 0, stream>>>(h1, offs, icnt, csr, w2h, w2l, b2, linW, batch, gs, gc,
                                        N);
  final_k<<<(G * 2 + 255) / 256, 256, 0, stream>>>(gs, gc, linb, out, G);
}

// Round 9
// 628.620 us; speedup vs baseline: 1.0458x; 1.0458x over previous
//
#include <hip/hip_runtime.h>
#include <hip/hip_bf16.h>

#define NREL 3
#define EMB 32
#define HID 64

typedef __attribute__((ext_vector_type(8))) short short8_t;
typedef __attribute__((ext_vector_type(4))) float f32x4;

__device__ inline short f2bf(float v) {
  __hip_bfloat16 b = __float2bfloat16(v);
  short s;
  __builtin_memcpy(&s, &b, 2);
  return s;
}
__device__ inline float bf2f(short s) {
  __hip_bfloat16 b;
  __builtin_memcpy(&b, &s, 2);
  return __bfloat162float(b);
}
// split 8 fp32 into bf16 hi + lo-residual fragments (in registers)
__device__ inline void split8(const float* v, short8_t* h, short8_t* l) {
#pragma unroll
  for (int i = 0; i < 8; i++) {
    short hh = f2bf(v[i]);
    (*h)[i] = hh;
    (*l)[i] = f2bf(v[i] - bf2f(hh));
  }
}

// ---------------- embedding materialize: x[n][0:32] fp32 ----------------
__global__ __launch_bounds__(256) void embed_k(
    const int* __restrict__ sid, const int* __restrict__ cid, const int* __restrict__ pid,
    const float* __restrict__ se, const float* __restrict__ ce, const float* __restrict__ pe,
    float* __restrict__ x, int N) {
  int i = blockIdx.x * 256 + threadIdx.x;
  if (i >= N * 8) return;
  int n = i >> 3, cg = i & 7;
  const float4 a = *(const float4*)&se[sid[n] * EMB + cg * 4];
  const float4 b = *(const float4*)&ce[cid[n] * EMB + cg * 4];
  const float4 c = *(const float4*)&pe[pid[n] * EMB + cg * 4];
  float4 v;
  v.x = a.x + b.x + c.x; v.y = a.y + b.y + c.y;
  v.z = a.z + b.z + c.z; v.w = a.w + b.w + c.w;
  *(float4*)&x[(size_t)n * EMB + cg * 4] = v;
}

// ---- weight prep: transpose+stack+split to bf16 hi/lo, n-major [64][K] ----
__global__ __launch_bounds__(256) void wprep_k(
    const float* __restrict__ root1, const float* __restrict__ W1,
    const float* __restrict__ root2, const float* __restrict__ W2,
    short* __restrict__ w1h, short* __restrict__ w1l,
    short* __restrict__ w2h, short* __restrict__ w2l) {
  int i = blockIdx.x * 256 + threadIdx.x;
  if (i < 64 * 128) {  // layer 1: K=128
    int k = i >> 6, n = i & 63;
    float v = (k < EMB) ? root1[k * 64 + n] : W1[(k - EMB) * 64 + n];
    short h = f2bf(v);
    w1h[n * 128 + k] = h;
    w1l[n * 128 + k] = f2bf(v - bf2f(h));
  }
  int j = i - 64 * 128;
  if (j >= 0 && j < 64 * 256) {  // layer 2: K=256
    int k = j >> 6, n = j & 63;
    float v = (k < HID) ? root2[k * 64 + n] : W2[(k - HID) * 64 + n];
    short h = f2bf(v);
    w2h[n * 256 + k] = h;
    w2l[n * 256 + k] = f2bf(v - bf2f(h));
  }
}

// ================= CSR build, RELATION-MAJOR: key = rel*N + dst =================
__global__ __launch_bounds__(256) void hist_k(const int* __restrict__ dst,
                                              const int* __restrict__ et,
                                              int* __restrict__ icnt, int E, int N) {
  int e = blockIdx.x * 256 + threadIdx.x;
  if (e >= E) return;
  atomicAdd(&icnt[et[e] * N + dst[e]], 1);
}

__global__ __launch_bounds__(256) void scan1_k(const int* __restrict__ icnt,
                                               int* __restrict__ psum, int M) {
  int base = blockIdx.x * 1024 + threadIdx.x * 4;
  int s = 0;
#pragma unroll
  for (int j = 0; j < 4; j++) {
    int i = base + j;
    if (i < M) s += icnt[i];
  }
  __shared__ int tmp[256];
  tmp[threadIdx.x] = s;
  __syncthreads();
  for (int off = 128; off > 0; off >>= 1) {
    if (threadIdx.x < off) tmp[threadIdx.x] += tmp[threadIdx.x + off];
    __syncthreads();
  }
  if (threadIdx.x == 0) psum[blockIdx.x] = tmp[0];
}

__global__ __launch_bounds__(256) void scan2_k(int* __restrict__ psum, int P) {
  __shared__ int tmp[256];
  __shared__ int carry_s;
  if (threadIdx.x == 0) carry_s = 0;
  __syncthreads();
  for (int base = 0; base < P; base += 256) {
    int i = base + threadIdx.x;
    int v = (i < P) ? psum[i] : 0;
    tmp[threadIdx.x] = v;
    __syncthreads();
    for (int off = 1; off < 256; off <<= 1) {
      int u = (threadIdx.x >= off) ? tmp[threadIdx.x - off] : 0;
      __syncthreads();
      tmp[threadIdx.x] += u;
      __syncthreads();
    }
    int carry = carry_s;
    if (i < P) psum[i] = carry + tmp[threadIdx.x] - v;
    __syncthreads();
    if (threadIdx.x == 0) carry_s = carry + tmp[255];
    __syncthreads();
  }
}

__global__ __launch_bounds__(256) void scan3_k(const int* __restrict__ icnt,
                                               const int* __restrict__ psum,
                                               int* __restrict__ offs, int M) {
  int base = blockIdx.x * 1024 + threadIdx.x * 4;
  int v[4];
  int s = 0;
#pragma unroll
  for (int j = 0; j < 4; j++) {
    int i = base + j;
    v[j] = (i < M) ? icnt[i] : 0;
    s += v[j];
  }
  __shared__ int tmp[256];
  tmp[threadIdx.x] = s;
  __syncthreads();
  for (int off = 1; off < 256; off <<= 1) {
    int u = (threadIdx.x >= off) ? tmp[threadIdx.x - off] : 0;
    __syncthreads();
    tmp[threadIdx.x] += u;
    __syncthreads();
  }
  int run = psum[blockIdx.x] + tmp[threadIdx.x] - s;
#pragma unroll
  for (int j = 0; j < 4; j++) {
    int i = base + j;
    if (i < M) {
      offs[i] = run;
      run += v[j];
    }
  }
}

__global__ __launch_bounds__(256) void scatter_k(const int* __restrict__ src,
                                                 const int* __restrict__ dst,
                                                 const int* __restrict__ et,
                                                 int* __restrict__ cursor,
                                                 int* __restrict__ csr, int E, int N) {
  int e = blockIdx.x * 256 + threadIdx.x;
  if (e >= E) return;
  int p = atomicAdd(&cursor[et[e] * N + dst[e]], 1);
  csr[p] = src[e];
}

// ====== layer-1 fused: register-fragment gather + split-bf16 MFMA -> h1 (fp32) ======
// No LDS, no barriers. Wave w owns nodes n0+16w..+15. Lane (m_,q): A-row m_, k-slice q*8.
// A groups (32 k each): sg0 = x(self), sg1..3 = mean_r. B from pre-split global (L2-resident).
__global__ __launch_bounds__(256) void l1fused_k(
    const float* __restrict__ x,
    const int* __restrict__ offs, const int* __restrict__ icnt, const int* __restrict__ csr,
    const short* __restrict__ wth, const short* __restrict__ wtl,
    const float* __restrict__ bias, float* __restrict__ h1, int N) {
  const int t = threadIdx.x;
  const int lane = t & 63, w = t >> 6;
  const int m_ = lane & 15, q = lane >> 4;
  const int n0 = blockIdx.x * 64 + w * 16;
  int n = n0 + m_;
  if (n >= N) n = N - 1;

  float a[4][8];
  {  // self slice
    float4 v0 = *(const float4*)&x[(size_t)n * EMB + q * 8];
    float4 v1 = *(const float4*)&x[(size_t)n * EMB + q * 8 + 4];
    a[0][0] = v0.x; a[0][1] = v0.y; a[0][2] = v0.z; a[0][3] = v0.w;
    a[0][4] = v1.x; a[0][5] = v1.y; a[0][6] = v1.z; a[0][7] = v1.w;
  }
  {  // merged 3-relation register walk
    int beg[NREL], len[NREL];
    int mx = 0;
#pragma unroll
    for (int r = 0; r < NREL; r++) {
      int idx = r * N + n;
      beg[r] = offs[idx];
      len[r] = icnt[idx];
      mx = max(mx, len[r]);
    }
#pragma unroll
    for (int r = 0; r < NREL; r++)
#pragma unroll
      for (int i = 0; i < 8; i++) a[1 + r][i] = 0.f;
    for (int j = 0; j < mx; j++) {
      int s[NREL];
#pragma unroll
      for (int r = 0; r < NREL; r++) s[r] = (j < len[r]) ? csr[beg[r] + j] : -1;
#pragma unroll
      for (int r = 0; r < NREL; r++)
        if (s[r] >= 0) {
          float4 v0 = *(const float4*)&x[(size_t)s[r] * EMB + q * 8];
          float4 v1 = *(const float4*)&x[(size_t)s[r] * EMB + q * 8 + 4];
          a[1 + r][0] += v0.x; a[1 + r][1] += v0.y; a[1 + r][2] += v0.z; a[1 + r][3] += v0.w;
          a[1 + r][4] += v1.x; a[1 + r][5] += v1.y; a[1 + r][6] += v1.z; a[1 + r][7] += v1.w;
        }
    }
#pragma unroll
    for (int r = 0; r < NREL; r++) {
      float inv = 1.f / fmaxf((float)len[r], 1.f);
#pragma unroll
      for (int i = 0; i < 8; i++) a[1 + r][i] *= inv;
    }
  }
  // convert to hi/lo fragments
  short8_t ah[4], al[4];
#pragma unroll
  for (int g = 0; g < 4; g++) split8(a[g], &ah[g], &al[g]);

  // MFMA: 4 n-tiles (tt), 4 k-groups, split-3
  f32x4 acc[4];
#pragma unroll
  for (int i = 0; i < 4; i++) acc[i] = (f32x4){0.f, 0.f, 0.f, 0.f};
#pragma unroll
  for (int tt = 0; tt < 4; tt++) {
    const size_t wrow = (size_t)(16 * tt + m_) * 128;
#pragma unroll
    for (int g = 0; g < 4; g++) {
      short8_t bh = *(const short8_t*)&wth[wrow + g * 32 + q * 8];
      short8_t bl = *(const short8_t*)&wtl[wrow + g * 32 + q * 8];
      acc[tt] = __builtin_amdgcn_mfma_f32_16x16x32_bf16(ah[g], bh, acc[tt], 0, 0, 0);
      acc[tt] = __builtin_amdgcn_mfma_f32_16x16x32_bf16(ah[g], bl, acc[tt], 0, 0, 0);
      acc[tt] = __builtin_amdgcn_mfma_f32_16x16x32_bf16(al[g], bh, acc[tt], 0, 0, 0);
    }
  }
  // epilogue: C layout col=lane&15 (out col within tile tt), row=q*4+reg (node)
#pragma unroll
  for (int tt = 0; tt < 4; tt++) {
    float bia = bias[16 * tt + m_];
#pragma unroll
    for (int reg = 0; reg < 4; reg++) {
      int node = n0 + q * 4 + reg;
      if (node < N) h1[(size_t)node * HID + 16 * tt + m_] = fmaxf(acc[tt][reg] + bia, 0.f);
    }
  }
}

// ====== layer-2 fused: register-fragment gather + split-bf16 MFMA + pooled epilogue ======
// A groups (64 k each = 2 sub-32): sg0 = h1(self), sg1..3 = mean_r.
__global__ __launch_bounds__(256) void l2fused_k(
    const float* __restrict__ h1,
    const int* __restrict__ offs, const int* __restrict__ icnt, const int* __restrict__ csr,
    const short* __restrict__ wth, const short* __restrict__ wtl,
    const float* __restrict__ bias, const float* __restrict__ linW,
    const int* __restrict__ batch, float* __restrict__ gs, float* __restrict__ gc, int N) {
  const int t = threadIdx.x;
  const int lane = t & 63, w = t >> 6;
  const int m_ = lane & 15, q = lane >> 4;
  const int n0 = blockIdx.x * 64 + w * 16;
  int n = n0 + m_;
  if (n >= N) n = N - 1;

  f32x4 acc[4];
#pragma unroll
  for (int i = 0; i < 4; i++) acc[i] = (f32x4){0.f, 0.f, 0.f, 0.f};

  // ---- self segment (k 0..63): immediate MFMA ----
  {
    float a[2][8];
    const float* p = &h1[(size_t)n * HID];
#pragma unroll
    for (int s_ = 0; s_ < 2; s_++) {
      float4 v0 = *(const float4*)&p[s_ * 32 + q * 8];
      float4 v1 = *(const float4*)&p[s_ * 32 + q * 8 + 4];
      a[s_][0] = v0.x; a[s_][1] = v0.y; a[s_][2] = v0.z; a[s_][3] = v0.w;
      a[s_][4] = v1.x; a[s_][5] = v1.y; a[s_][6] = v1.z; a[s_][7] = v1.w;
    }
    short8_t ah[2], al[2];
    split8(a[0], &ah[0], &al[0]);
    split8(a[1], &ah[1], &al[1]);
#pragma unroll
    for (int tt = 0; tt < 4; tt++) {
      const size_t wrow = (size_t)(16 * tt + m_) * 256;
#pragma unroll
      for (int s_ = 0; s_ < 2; s_++) {
        short8_t bh = *(const short8_t*)&wth[wrow + s_ * 32 + q * 8];
        short8_t bl = *(const short8_t*)&wtl[wrow + s_ * 32 + q * 8];
        acc[tt] = __builtin_amdgcn_mfma_f32_16x16x32_bf16(ah[s_], bh, acc[tt], 0, 0, 0);
        acc[tt] = __builtin_amdgcn_mfma_f32_16x16x32_bf16(ah[s_], bl, acc[tt], 0, 0, 0);
        acc[tt] = __builtin_amdgcn_mfma_f32_16x16x32_bf16(al[s_], bh, acc[tt], 0, 0, 0);
      }
    }
  }
  // ---- merged 3-relation register walk: lane accumulates its 16-float row-slice ----
  {
    int beg[NREL], len[NREL];
    int mx = 0;
#pragma unroll
    for (int r = 0; r < NREL; r++) {
      int idx = r * N + n;
      beg[r] = offs[idx];
      len[r] = icnt[idx];
      mx = max(mx, len[r]);
    }
    float a[NREL][2][8];
#pragma unroll
    for (int r = 0; r < NREL; r++)
#pragma unroll
      for (int s_ = 0; s_ < 2; s_++)
#pragma unroll
        for (int i = 0; i < 8; i++) a[r][s_][i] = 0.f;
    for (int j = 0; j < mx; j++) {
      int s[NREL];
#pragma unroll
      for (int r = 0; r < NREL; r++) s[r] = (j < len[r]) ? csr[beg[r] + j] : -1;
#pragma unroll
      for (int r = 0; r < NREL; r++)
        if (s[r] >= 0) {
          const float* p = &h1[(size_t)s[r] * HID];
#pragma unroll
          for (int s_ = 0; s_ < 2; s_++) {
            float4 v0 = *(const float4*)&p[s_ * 32 + q * 8];
            float4 v1 = *(const float4*)&p[s_ * 32 + q * 8 + 4];
            a[r][s_][0] += v0.x; a[r][s_][1] += v0.y; a[r][s_][2] += v0.z; a[r][s_][3] += v0.w;
            a[r][s_][4] += v1.x; a[r][s_][5] += v1.y; a[r][s_][6] += v1.z; a[r][s_][7] += v1.w;
          }
        }
    }
#pragma unroll
    for (int r = 0; r < NREL; r++) {
      float inv = 1.f / fmaxf((float)len[r], 1.f);
      short8_t ah[2], al[2];
#pragma unroll
      for (int s_ = 0; s_ < 2; s_++) {
#pragma unroll
        for (int i = 0; i < 8; i++) a[r][s_][i] *= inv;
        split8(a[r][s_], &ah[s_], &al[s_]);
      }
#pragma unroll
      for (int tt = 0; tt < 4; tt++) {
        const size_t wrow = (size_t)(16 * tt + m_) * 256;
#pragma unroll
        for (int s_ = 0; s_ < 2; s_++) {
          short8_t bh = *(const short8_t*)&wth[wrow + (1 + r) * 64 + s_ * 32 + q * 8];
          short8_t bl = *(const short8_t*)&wtl[wrow + (1 + r) * 64 + s_ * 32 + q * 8];
          acc[tt] = __builtin_amdgcn_mfma_f32_16x16x32_bf16(ah[s_], bh, acc[tt], 0, 0, 0);
          acc[tt] = __builtin_amdgcn_mfma_f32_16x16x32_bf16(ah[s_], bl, acc[tt], 0, 0, 0);
          acc[tt] = __builtin_amdgcn_mfma_f32_16x16x32_bf16(al[s_], bh, acc[tt], 0, 0, 0);
        }
      }
    }
  }
  // pooled epilogue: bias+relu, 64->2, reduce across m_ lanes, atomics
  float bia[4], lw0[4], lw1[4];
#pragma unroll
  for (int tt = 0; tt < 4; tt++) {
    int col = 16 * tt + m_;
    bia[tt] = bias[col];
    lw0[tt] = linW[col * 2 + 0];
    lw1[tt] = linW[col * 2 + 1];
  }
#pragma unroll
  for (int reg = 0; reg < 4; reg++) {
    int node = n0 + q * 4 + reg;
    float p0 = 0.f, p1 = 0.f;
#pragma unroll
    for (int tt = 0; tt < 4; tt++) {
      float v = fmaxf(acc[tt][reg] + bia[tt], 0.f);
      p0 += v * lw0[tt];
      p1 += v * lw1[tt];
    }
#pragma unroll
    for (int o = 1; o < 16; o <<= 1) {
      p0 += __shfl_xor(p0, o, 64);
      p1 += __shfl_xor(p1, o, 64);
    }
    if (m_ == 0 && node < N) {
      int g = batch[node];
      atomicAdd(&gs[g * 2 + 0], p0);
      atomicAdd(&gs[g * 2 + 1], p1);
      atomicAdd(&gc[g], 1.0f);
    }
  }
}

__global__ __launch_bounds__(256) void final_k(const float* __restrict__ gs,
                                               const float* __restrict__ gc,
                                               const float* __restrict__ linb,
                                               float* __restrict__ out, int G) {
  int i = blockIdx.x * 256 + threadIdx.x;
  if (i >= G * 2) return;
  int g = i >> 1, o = i & 1;
  out[i] = gs[i] / fmaxf(gc[g], 1.0f) + linb[o];
}

extern "C" void kernel_launch(void* const* d_in, const int* in_sizes, int n_in,
                              void* d_out, int out_size, void* d_ws, size_t ws_size,
                              hipStream_t stream) {
  const int* sid = (const int*)d_in[0];
  const int* cid = (const int*)d_in[1];
  const int* pid = (const int*)d_in[2];
  const int* ei = (const int*)d_in[3];
  const int* et = (const int*)d_in[4];
  const int* batch = (const int*)d_in[5];
  const float* se = (const float*)d_in[7];
  const float* ce = (const float*)d_in[8];
  const float* pe = (const float*)d_in[9];
  const float* W1 = (const float*)d_in[10];
  const float* root1 = (const float*)d_in[11];
  const float* b1 = (const float*)d_in[12];
  const float* W2 = (const float*)d_in[13];
  const float* root2 = (const float*)d_in[14];
  const float* b2 = (const float*)d_in[15];
  const float* linW = (const float*)d_in[16];
  const float* linb = (const float*)d_in[17];
  float* out = (float*)d_out;

  const int N = in_sizes[0];
  const int E = in_sizes[4];
  const int G = out_size / 2;
  const int* src = ei;
  const int* dst = ei + E;
  const int M = N * NREL;
  const int P = (M + 1023) / 1024;

  // ---- workspace layout (strictly budgeted) ----
  char* w = (char*)d_ws;
  float* h1 = (float*)w;   w += (size_t)N * HID * sizeof(float);
  float* x = (float*)w;    w += (size_t)N * EMB * sizeof(float);
  float* gs = (float*)w;   w += (size_t)G * 2 * sizeof(float);
  float* gc = (float*)w;   w += (size_t)G * sizeof(float);
  int* icnt = (int*)w;     w += (size_t)M * sizeof(int);
  int* offs = (int*)w;     w += (size_t)M * sizeof(int);
  int* cursor = (int*)w;   w += (size_t)M * sizeof(int);
  int* csr = (int*)w;      w += (size_t)E * sizeof(int);
  short* w1h = (short*)w;  w += (size_t)64 * 128 * sizeof(short);
  short* w1l = (short*)w;  w += (size_t)64 * 128 * sizeof(short);
  short* w2h = (short*)w;  w += (size_t)64 * 256 * sizeof(short);
  short* w2l = (short*)w;  w += (size_t)64 * 256 * sizeof(short);
  int* psum = (int*)w;     w += (size_t)P * sizeof(int);
  if ((size_t)(w - (char*)d_ws) > ws_size) return;  // fail loudly, no OOB

  hipMemsetAsync(icnt, 0, (size_t)M * sizeof(int), stream);
  hipMemsetAsync(gs, 0, (size_t)G * 3 * sizeof(float), stream);

  wprep_k<<<(64 * 128 + 64 * 256 + 255) / 256, 256, 0, stream>>>(root1, W1, root2, W2, w1h, w1l,
                                                                 w2h, w2l);
  embed_k<<<(N * 8 + 255) / 256, 256, 0, stream>>>(sid, cid, pid, se, ce, pe, x, N);
  hist_k<<<(E + 255) / 256, 256, 0, stream>>>(dst, et, icnt, E, N);
  scan1_k<<<P, 256, 0, stream>>>(icnt, psum, M);
  scan2_k<<<1, 256, 0, stream>>>(psum, P);
  scan3_k<<<P, 256, 0, stream>>>(icnt, psum, offs, M);
  hipMemcpyAsync(cursor, offs, (size_t)M * sizeof(int), hipMemcpyDeviceToDevice, stream);
  scatter_k<<<(E + 255) / 256, 256, 0, stream>>>(src, dst, et, cursor, csr, E, N);

  int blocks = (N + 63) / 64;
  l1fused_k<<<blocks, 256, 0, stream>>>(x, offs, icnt, csr, w1h, w1l, b1, h1, N);
  l2fused_k<<<blocks, 256, 0, stream>>>(h1, offs, icnt, csr, w2h, w2l, b2, linW, batch, gs, gc,
                                        N);
  final_k<<<(G * 2 + 255) / 256, 256, 0, stream>>>(gs, gc, linb, out, G);
}

// Round 10
// 602.486 us; speedup vs baseline: 1.0911x; 1.0434x over previous
//
#include <hip/hip_runtime.h>
#include <hip/hip_bf16.h>

#define NREL 3
#define EMB 32
#define HID 64

typedef __attribute__((ext_vector_type(8))) short short8_t;
typedef __attribute__((ext_vector_type(4))) short short4_t;
typedef __attribute__((ext_vector_type(4))) float f32x4;

__device__ inline short f2bf(float v) {
  __hip_bfloat16 b = __float2bfloat16(v);
  short s;
  __builtin_memcpy(&s, &b, 2);
  return s;
}
__device__ inline float bf2f(short s) {
  __hip_bfloat16 b;
  __builtin_memcpy(&b, &s, 2);
  return __bfloat162float(b);
}
// split 8 fp32 into bf16 hi + lo-residual fragments (in registers)
__device__ inline void split8(const float* v, short8_t* h, short8_t* l) {
#pragma unroll
  for (int i = 0; i < 8; i++) {
    short hh = f2bf(v[i]);
    (*h)[i] = hh;
    (*l)[i] = f2bf(v[i] - bf2f(hh));
  }
}

// ------------- embedding materialize: x -> hi/lo bf16 planes -------------
__global__ __launch_bounds__(256) void embed_k(
    const int* __restrict__ sid, const int* __restrict__ cid, const int* __restrict__ pid,
    const float* __restrict__ se, const float* __restrict__ ce, const float* __restrict__ pe,
    short* __restrict__ xh, short* __restrict__ xl, int N) {
  int i = blockIdx.x * 256 + threadIdx.x;
  if (i >= N * 8) return;
  int n = i >> 3, cg = i & 7;
  const float4 a = *(const float4*)&se[sid[n] * EMB + cg * 4];
  const float4 b = *(const float4*)&ce[cid[n] * EMB + cg * 4];
  const float4 c = *(const float4*)&pe[pid[n] * EMB + cg * 4];
  float v[4];
  v[0] = a.x + b.x + c.x; v[1] = a.y + b.y + c.y;
  v[2] = a.z + b.z + c.z; v[3] = a.w + b.w + c.w;
  short4_t h, l;
#pragma unroll
  for (int j = 0; j < 4; j++) {
    short hh = f2bf(v[j]);
    h[j] = hh;
    l[j] = f2bf(v[j] - bf2f(hh));
  }
  *(short4_t*)&xh[(size_t)n * EMB + cg * 4] = h;
  *(short4_t*)&xl[(size_t)n * EMB + cg * 4] = l;
}

// ---- weight prep: transpose+stack+split to bf16 hi/lo, n-major [64][K] ----
__global__ __launch_bounds__(256) void wprep_k(
    const float* __restrict__ root1, const float* __restrict__ W1,
    const float* __restrict__ root2, const float* __restrict__ W2,
    short* __restrict__ w1h, short* __restrict__ w1l,
    short* __restrict__ w2h, short* __restrict__ w2l) {
  int i = blockIdx.x * 256 + threadIdx.x;
  if (i < 64 * 128) {  // layer 1: K=128
    int k = i >> 6, n = i & 63;
    float v = (k < EMB) ? root1[k * 64 + n] : W1[(k - EMB) * 64 + n];
    short h = f2bf(v);
    w1h[n * 128 + k] = h;
    w1l[n * 128 + k] = f2bf(v - bf2f(h));
  }
  int j = i - 64 * 128;
  if (j >= 0 && j < 64 * 256) {  // layer 2: K=256
    int k = j >> 6, n = j & 63;
    float v = (k < HID) ? root2[k * 64 + n] : W2[(k - HID) * 64 + n];
    short h = f2bf(v);
    w2h[n * 256 + k] = h;
    w2l[n * 256 + k] = f2bf(v - bf2f(h));
  }
}

// ================= CSR build, RELATION-MAJOR: key = rel*N + dst =================
__global__ __launch_bounds__(256) void hist_k(const int* __restrict__ dst,
                                              const int* __restrict__ et,
                                              int* __restrict__ icnt, int E, int N) {
  int e = blockIdx.x * 256 + threadIdx.x;
  if (e >= E) return;
  atomicAdd(&icnt[et[e] * N + dst[e]], 1);
}

__global__ __launch_bounds__(256) void scan1_k(const int* __restrict__ icnt,
                                               int* __restrict__ psum, int M) {
  int base = blockIdx.x * 1024 + threadIdx.x * 4;
  int s = 0;
#pragma unroll
  for (int j = 0; j < 4; j++) {
    int i = base + j;
    if (i < M) s += icnt[i];
  }
  __shared__ int tmp[256];
  tmp[threadIdx.x] = s;
  __syncthreads();
  for (int off = 128; off > 0; off >>= 1) {
    if (threadIdx.x < off) tmp[threadIdx.x] += tmp[threadIdx.x + off];
    __syncthreads();
  }
  if (threadIdx.x == 0) psum[blockIdx.x] = tmp[0];
}

__global__ __launch_bounds__(256) void scan2_k(int* __restrict__ psum, int P) {
  __shared__ int tmp[256];
  __shared__ int carry_s;
  if (threadIdx.x == 0) carry_s = 0;
  __syncthreads();
  for (int base = 0; base < P; base += 256) {
    int i = base + threadIdx.x;
    int v = (i < P) ? psum[i] : 0;
    tmp[threadIdx.x] = v;
    __syncthreads();
    for (int off = 1; off < 256; off <<= 1) {
      int u = (threadIdx.x >= off) ? tmp[threadIdx.x - off] : 0;
      __syncthreads();
      tmp[threadIdx.x] += u;
      __syncthreads();
    }
    int carry = carry_s;
    if (i < P) psum[i] = carry + tmp[threadIdx.x] - v;
    __syncthreads();
    if (threadIdx.x == 0) carry_s = carry + tmp[255];
    __syncthreads();
  }
}

__global__ __launch_bounds__(256) void scan3_k(const int* __restrict__ icnt,
                                               const int* __restrict__ psum,
                                               int* __restrict__ offs, int M) {
  int base = blockIdx.x * 1024 + threadIdx.x * 4;
  int v[4];
  int s = 0;
#pragma unroll
  for (int j = 0; j < 4; j++) {
    int i = base + j;
    v[j] = (i < M) ? icnt[i] : 0;
    s += v[j];
  }
  __shared__ int tmp[256];
  tmp[threadIdx.x] = s;
  __syncthreads();
  for (int off = 1; off < 256; off <<= 1) {
    int u = (threadIdx.x >= off) ? tmp[threadIdx.x - off] : 0;
    __syncthreads();
    tmp[threadIdx.x] += u;
    __syncthreads();
  }
  int run = psum[blockIdx.x] + tmp[threadIdx.x] - s;
#pragma unroll
  for (int j = 0; j < 4; j++) {
    int i = base + j;
    if (i < M) {
      offs[i] = run;
      run += v[j];
    }
  }
}

__global__ __launch_bounds__(256) void scatter_k(const int* __restrict__ src,
                                                 const int* __restrict__ dst,
                                                 const int* __restrict__ et,
                                                 int* __restrict__ cursor,
                                                 int* __restrict__ csr, int E, int N) {
  int e = blockIdx.x * 256 + threadIdx.x;
  if (e >= E) return;
  int p = atomicAdd(&cursor[et[e] * N + dst[e]], 1);
  csr[p] = src[e];
}

// ====== layer-1 fused: bf16-plane gather + split-bf16 MFMA -> h1 hi/lo planes ======
// No LDS, no barriers. Wave w: nodes n0+16w..+15. Lane (m_,q): A-row m_, k-slice q*8.
__global__ __launch_bounds__(256) void l1fused_k(
    const short* __restrict__ xh, const short* __restrict__ xl,
    const int* __restrict__ offs, const int* __restrict__ icnt, const int* __restrict__ csr,
    const short* __restrict__ wth, const short* __restrict__ wtl,
    const float* __restrict__ bias, short* __restrict__ h1h, short* __restrict__ h1l, int N) {
  const int t = threadIdx.x;
  const int lane = t & 63, w = t >> 6;
  const int m_ = lane & 15, q = lane >> 4;
  const int n0 = blockIdx.x * 64 + w * 16;
  int n = n0 + m_;
  if (n >= N) n = N - 1;

  // self fragments: direct hi/lo plane loads (16-bit-accurate x)
  short8_t ah0 = *(const short8_t*)&xh[(size_t)n * EMB + q * 8];
  short8_t al0 = *(const short8_t*)&xl[(size_t)n * EMB + q * 8];

  // merged 3-relation register walk on xh (hi plane only), csr 2-deep pipelined
  float a[NREL][8];
#pragma unroll
  for (int r = 0; r < NREL; r++)
#pragma unroll
    for (int i = 0; i < 8; i++) a[r][i] = 0.f;
  int beg[NREL], len[NREL];
  int mx = 0;
#pragma unroll
  for (int r = 0; r < NREL; r++) {
    int idx = r * N + n;
    beg[r] = offs[idx];
    len[r] = icnt[idx];
    mx = max(mx, len[r]);
  }
  int scur[NREL];
#pragma unroll
  for (int r = 0; r < NREL; r++) scur[r] = (0 < len[r]) ? csr[beg[r]] : -1;
  for (int j = 0; j < mx; j++) {
    int snxt[NREL];
#pragma unroll
    for (int r = 0; r < NREL; r++) snxt[r] = (j + 1 < len[r]) ? csr[beg[r] + j + 1] : -1;
#pragma unroll
    for (int r = 0; r < NREL; r++)
      if (scur[r] >= 0) {
        short8_t v = *(const short8_t*)&xh[(size_t)scur[r] * EMB + q * 8];
#pragma unroll
        for (int i = 0; i < 8; i++) a[r][i] += bf2f(v[i]);
      }
#pragma unroll
    for (int r = 0; r < NREL; r++) scur[r] = snxt[r];
  }
  short8_t ahn[NREL], aln[NREL];
#pragma unroll
  for (int r = 0; r < NREL; r++) {
    float inv = 1.f / fmaxf((float)len[r], 1.f);
#pragma unroll
    for (int i = 0; i < 8; i++) a[r][i] *= inv;
    split8(a[r], &ahn[r], &aln[r]);
  }

  // MFMA: 4 n-tiles (tt) x 4 k-groups x split-3
  f32x4 acc[4];
#pragma unroll
  for (int i = 0; i < 4; i++) acc[i] = (f32x4){0.f, 0.f, 0.f, 0.f};
#pragma unroll
  for (int tt = 0; tt < 4; tt++) {
    const size_t wrow = (size_t)(16 * tt + m_) * 128;
#pragma unroll
    for (int g = 0; g < 4; g++) {
      short8_t bh = *(const short8_t*)&wth[wrow + g * 32 + q * 8];
      short8_t bl = *(const short8_t*)&wtl[wrow + g * 32 + q * 8];
      short8_t ah = (g == 0) ? ah0 : ahn[g - 1];
      short8_t al = (g == 0) ? al0 : aln[g - 1];
      acc[tt] = __builtin_amdgcn_mfma_f32_16x16x32_bf16(ah, bh, acc[tt], 0, 0, 0);
      acc[tt] = __builtin_amdgcn_mfma_f32_16x16x32_bf16(ah, bl, acc[tt], 0, 0, 0);
      acc[tt] = __builtin_amdgcn_mfma_f32_16x16x32_bf16(al, bh, acc[tt], 0, 0, 0);
    }
  }
  // epilogue: C layout col=lane&15, row=q*4+reg -> h1 hi/lo planes + relu
#pragma unroll
  for (int tt = 0; tt < 4; tt++) {
    float bia = bias[16 * tt + m_];
#pragma unroll
    for (int reg = 0; reg < 4; reg++) {
      int node = n0 + q * 4 + reg;
      if (node < N) {
        float val = fmaxf(acc[tt][reg] + bia, 0.f);
        short hh = f2bf(val);
        h1h[(size_t)node * HID + 16 * tt + m_] = hh;
        h1l[(size_t)node * HID + 16 * tt + m_] = f2bf(val - bf2f(hh));
      }
    }
  }
}

// ====== layer-2 fused: bf16-plane gather + split-bf16 MFMA + pooled epilogue ======
__global__ __launch_bounds__(256) void l2fused_k(
    const short* __restrict__ h1h, const short* __restrict__ h1l,
    const int* __restrict__ offs, const int* __restrict__ icnt, const int* __restrict__ csr,
    const short* __restrict__ wth, const short* __restrict__ wtl,
    const float* __restrict__ bias, const float* __restrict__ linW,
    const int* __restrict__ batch, float* __restrict__ gs, float* __restrict__ gc, int N) {
  const int t = threadIdx.x;
  const int lane = t & 63, w = t >> 6;
  const int m_ = lane & 15, q = lane >> 4;
  const int n0 = blockIdx.x * 64 + w * 16;
  int n = n0 + m_;
  if (n >= N) n = N - 1;

  f32x4 acc[4];
#pragma unroll
  for (int i = 0; i < 4; i++) acc[i] = (f32x4){0.f, 0.f, 0.f, 0.f};

  // ---- self segment (k 0..63): direct hi/lo fragment loads ----
  {
    short8_t ah[2], al[2];
#pragma unroll
    for (int s_ = 0; s_ < 2; s_++) {
      ah[s_] = *(const short8_t*)&h1h[(size_t)n * HID + s_ * 32 + q * 8];
      al[s_] = *(const short8_t*)&h1l[(size_t)n * HID + s_ * 32 + q * 8];
    }
#pragma unroll
    for (int tt = 0; tt < 4; tt++) {
      const size_t wrow = (size_t)(16 * tt + m_) * 256;
#pragma unroll
      for (int s_ = 0; s_ < 2; s_++) {
        short8_t bh = *(const short8_t*)&wth[wrow + s_ * 32 + q * 8];
        short8_t bl = *(const short8_t*)&wtl[wrow + s_ * 32 + q * 8];
        acc[tt] = __builtin_amdgcn_mfma_f32_16x16x32_bf16(ah[s_], bh, acc[tt], 0, 0, 0);
        acc[tt] = __builtin_amdgcn_mfma_f32_16x16x32_bf16(ah[s_], bl, acc[tt], 0, 0, 0);
        acc[tt] = __builtin_amdgcn_mfma_f32_16x16x32_bf16(al[s_], bh, acc[tt], 0, 0, 0);
      }
    }
  }
  // ---- merged 3-relation register walk on h1h (hi plane only), csr pipelined ----
  {
    int beg[NREL], len[NREL];
    int mx = 0;
#pragma unroll
    for (int r = 0; r < NREL; r++) {
      int idx = r * N + n;
      beg[r] = offs[idx];
      len[r] = icnt[idx];
      mx = max(mx, len[r]);
    }
    float a[NREL][2][8];
#pragma unroll
    for (int r = 0; r < NREL; r++)
#pragma unroll
      for (int s_ = 0; s_ < 2; s_++)
#pragma unroll
        for (int i = 0; i < 8; i++) a[r][s_][i] = 0.f;
    int scur[NREL];
#pragma unroll
    for (int r = 0; r < NREL; r++) scur[r] = (0 < len[r]) ? csr[beg[r]] : -1;
    for (int j = 0; j < mx; j++) {
      int snxt[NREL];
#pragma unroll
      for (int r = 0; r < NREL; r++) snxt[r] = (j + 1 < len[r]) ? csr[beg[r] + j + 1] : -1;
#pragma unroll
      for (int r = 0; r < NREL; r++)
        if (scur[r] >= 0) {
          const short* p = &h1h[(size_t)scur[r] * HID];
#pragma unroll
          for (int s_ = 0; s_ < 2; s_++) {
            short8_t v = *(const short8_t*)&p[s_ * 32 + q * 8];
#pragma unroll
            for (int i = 0; i < 8; i++) a[r][s_][i] += bf2f(v[i]);
          }
        }
#pragma unroll
      for (int r = 0; r < NREL; r++) scur[r] = snxt[r];
    }
#pragma unroll
    for (int r = 0; r < NREL; r++) {
      float inv = 1.f / fmaxf((float)len[r], 1.f);
      short8_t ah[2], al[2];
#pragma unroll
      for (int s_ = 0; s_ < 2; s_++) {
#pragma unroll
        for (int i = 0; i < 8; i++) a[r][s_][i] *= inv;
        split8(a[r][s_], &ah[s_], &al[s_]);
      }
#pragma unroll
      for (int tt = 0; tt < 4; tt++) {
        const size_t wrow = (size_t)(16 * tt + m_) * 256;
#pragma unroll
        for (int s_ = 0; s_ < 2; s_++) {
          short8_t bh = *(const short8_t*)&wth[wrow + (1 + r) * 64 + s_ * 32 + q * 8];
          short8_t bl = *(const short8_t*)&wtl[wrow + (1 + r) * 64 + s_ * 32 + q * 8];
          acc[tt] = __builtin_amdgcn_mfma_f32_16x16x32_bf16(ah[s_], bh, acc[tt], 0, 0, 0);
          acc[tt] = __builtin_amdgcn_mfma_f32_16x16x32_bf16(ah[s_], bl, acc[tt], 0, 0, 0);
          acc[tt] = __builtin_amdgcn_mfma_f32_16x16x32_bf16(al[s_], bh, acc[tt], 0, 0, 0);
        }
      }
    }
  }
  // pooled epilogue: bias+relu, 64->2, reduce across m_ lanes, atomics
  float bia[4], lw0[4], lw1[4];
#pragma unroll
  for (int tt = 0; tt < 4; tt++) {
    int col = 16 * tt + m_;
    bia[tt] = bias[col];
    lw0[tt] = linW[col * 2 + 0];
    lw1[tt] = linW[col * 2 + 1];
  }
#pragma unroll
  for (int reg = 0; reg < 4; reg++) {
    int node = n0 + q * 4 + reg;
    float p0 = 0.f, p1 = 0.f;
#pragma unroll
    for (int tt = 0; tt < 4; tt++) {
      float v = fmaxf(acc[tt][reg] + bia[tt], 0.f);
      p0 += v * lw0[tt];
      p1 += v * lw1[tt];
    }
#pragma unroll
    for (int o = 1; o < 16; o <<= 1) {
      p0 += __shfl_xor(p0, o, 64);
      p1 += __shfl_xor(p1, o, 64);
    }
    if (m_ == 0 && node < N) {
      int g = batch[node];
      atomicAdd(&gs[g * 2 + 0], p0);
      atomicAdd(&gs[g * 2 + 1], p1);
      atomicAdd(&gc[g], 1.0f);
    }
  }
}

__global__ __launch_bounds__(256) void final_k(const float* __restrict__ gs,
                                               const float* __restrict__ gc,
                                               const float* __restrict__ linb,
                                               float* __restrict__ out, int G) {
  int i = blockIdx.x * 256 + threadIdx.x;
  if (i >= G * 2) return;
  int g = i >> 1, o = i & 1;
  out[i] = gs[i] / fmaxf(gc[g], 1.0f) + linb[o];
}

extern "C" void kernel_launch(void* const* d_in, const int* in_sizes, int n_in,
                              void* d_out, int out_size, void* d_ws, size_t ws_size,
                              hipStream_t stream) {
  const int* sid = (const int*)d_in[0];
  const int* cid = (const int*)d_in[1];
  const int* pid = (const int*)d_in[2];
  const int* ei = (const int*)d_in[3];
  const int* et = (const int*)d_in[4];
  const int* batch = (const int*)d_in[5];
  const float* se = (const float*)d_in[7];
  const float* ce = (const float*)d_in[8];
  const float* pe = (const float*)d_in[9];
  const float* W1 = (const float*)d_in[10];
  const float* root1 = (const float*)d_in[11];
  const float* b1 = (const float*)d_in[12];
  const float* W2 = (const float*)d_in[13];
  const float* root2 = (const float*)d_in[14];
  const float* b2 = (const float*)d_in[15];
  const float* linW = (const float*)d_in[16];
  const float* linb = (const float*)d_in[17];
  float* out = (float*)d_out;

  const int N = in_sizes[0];
  const int E = in_sizes[4];
  const int G = out_size / 2;
  const int* src = ei;
  const int* dst = ei + E;
  const int M = N * NREL;
  const int P = (M + 1023) / 1024;

  // ---- workspace layout (strictly budgeted; all offsets 16B-aligned) ----
  char* w = (char*)d_ws;
  short* h1h = (short*)w;  w += (size_t)N * HID * sizeof(short);
  short* h1l = (short*)w;  w += (size_t)N * HID * sizeof(short);
  short* xh = (short*)w;   w += (size_t)N * EMB * sizeof(short);
  short* xl = (short*)w;   w += (size_t)N * EMB * sizeof(short);
  float* gs = (float*)w;   w += (size_t)G * 2 * sizeof(float);
  float* gc = (float*)w;   w += (size_t)G * sizeof(float);
  int* icnt = (int*)w;     w += (size_t)M * sizeof(int);
  int* offs = (int*)w;     w += (size_t)M * sizeof(int);
  int* cursor = (int*)w;   w += (size_t)M * sizeof(int);
  int* csr = (int*)w;      w += (size_t)E * sizeof(int);
  short* w1h = (short*)w;  w += (size_t)64 * 128 * sizeof(short);
  short* w1l = (short*)w;  w += (size_t)64 * 128 * sizeof(short);
  short* w2h = (short*)w;  w += (size_t)64 * 256 * sizeof(short);
  short* w2l = (short*)w;  w += (size_t)64 * 256 * sizeof(short);
  int* psum = (int*)w;     w += (size_t)P * sizeof(int);
  if ((size_t)(w - (char*)d_ws) > ws_size) return;  // fail loudly, no OOB

  hipMemsetAsync(icnt, 0, (size_t)M * sizeof(int), stream);
  hipMemsetAsync(gs, 0, (size_t)G * 3 * sizeof(float), stream);

  wprep_k<<<(64 * 128 + 64 * 256 + 255) / 256, 256, 0, stream>>>(root1, W1, root2, W2, w1h, w1l,
                                                                 w2h, w2l);
  embed_k<<<(N * 8 + 255) / 256, 256, 0, stream>>>(sid, cid, pid, se, ce, pe, xh, xl, N);
  hist_k<<<(E + 255) / 256, 256, 0, stream>>>(dst, et, icnt, E, N);
  scan1_k<<<P, 256, 0, stream>>>(icnt, psum, M);
  scan2_k<<<1, 256, 0, stream>>>(psum, P);
  scan3_k<<<P, 256, 0, stream>>>(icnt, psum, offs, M);
  hipMemcpyAsync(cursor, offs, (size_t)M * sizeof(int), hipMemcpyDeviceToDevice, stream);
  scatter_k<<<(E + 255) / 256, 256, 0, stream>>>(src, dst, et, cursor, csr, E, N);

  int blocks = (N + 63) / 64;
  l1fused_k<<<blocks, 256, 0, stream>>>(xh, xl, offs, icnt, csr, w1h, w1l, b1, h1h, h1l, N);
  l2fused_k<<<blocks, 256, 0, stream>>>(h1h, h1l, offs, icnt, csr, w2h, w2l, b2, linW, batch,
                                        gs, gc, N);
  final_k<<<(G * 2 + 255) / 256, 256, 0, stream>>>(gs, gc, linb, out, G);
}

// Round 11
// 589.117 us; speedup vs baseline: 1.1159x; 1.0227x over previous
//
#include <hip/hip_runtime.h>
#include <hip/hip_bf16.h>

#define NREL 3
#define EMB 32
#define HID 64

typedef __attribute__((ext_vector_type(8))) short short8_t;
typedef __attribute__((ext_vector_type(4))) short short4_t;
typedef __attribute__((ext_vector_type(4))) float f32x4;

__device__ inline short f2bf(float v) {
  __hip_bfloat16 b = __float2bfloat16(v);
  short s;
  __builtin_memcpy(&s, &b, 2);
  return s;
}
__device__ inline float bf2f(short s) {
  __hip_bfloat16 b;
  __builtin_memcpy(&b, &s, 2);
  return __bfloat162float(b);
}
__device__ inline void split8(const float* v, short8_t* h, short8_t* l) {
#pragma unroll
  for (int i = 0; i < 8; i++) {
    short hh = f2bf(v[i]);
    (*h)[i] = hh;
    (*l)[i] = f2bf(v[i] - bf2f(hh));
  }
}

// ---- fused prep: embedding (hi/lo planes) + edge histogram + weight prep ----
__global__ __launch_bounds__(256) void prep_k(
    const int* __restrict__ sid, const int* __restrict__ cid, const int* __restrict__ pid,
    const float* __restrict__ se, const float* __restrict__ ce, const float* __restrict__ pe,
    short* __restrict__ xh, short* __restrict__ xl,
    const int* __restrict__ dst, const int* __restrict__ et, int* __restrict__ icnt,
    const float* __restrict__ root1, const float* __restrict__ W1,
    const float* __restrict__ root2, const float* __restrict__ W2,
    short* __restrict__ w1h, short* __restrict__ w1l,
    short* __restrict__ w2h, short* __restrict__ w2l, int N, int E) {
  int i = blockIdx.x * 256 + threadIdx.x;
  if (i < N * 8) {  // embedding: one float4 slice per thread
    int n = i >> 3, cg = i & 7;
    const float4 a = *(const float4*)&se[sid[n] * EMB + cg * 4];
    const float4 b = *(const float4*)&ce[cid[n] * EMB + cg * 4];
    const float4 c = *(const float4*)&pe[pid[n] * EMB + cg * 4];
    float v[4];
    v[0] = a.x + b.x + c.x; v[1] = a.y + b.y + c.y;
    v[2] = a.z + b.z + c.z; v[3] = a.w + b.w + c.w;
    short4_t h, l;
#pragma unroll
    for (int j = 0; j < 4; j++) {
      short hh = f2bf(v[j]);
      h[j] = hh;
      l[j] = f2bf(v[j] - bf2f(hh));
    }
    *(short4_t*)&xh[(size_t)n * EMB + cg * 4] = h;
    *(short4_t*)&xl[(size_t)n * EMB + cg * 4] = l;
  }
  if (i < E) atomicAdd(&icnt[et[i] * N + dst[i]], 1);
  if (i < 64 * 128) {  // layer-1 weights
    int k = i >> 6, n = i & 63;
    float v = (k < EMB) ? root1[k * 64 + n] : W1[(k - EMB) * 64 + n];
    short h = f2bf(v);
    w1h[n * 128 + k] = h;
    w1l[n * 128 + k] = f2bf(v - bf2f(h));
  }
  if (i < 64 * 256) {  // layer-2 weights
    int k = i >> 6, n = i & 63;
    float v = (k < HID) ? root2[k * 64 + n] : W2[(k - HID) * 64 + n];
    short h = f2bf(v);
    w2h[n * 256 + k] = h;
    w2l[n * 256 + k] = f2bf(v - bf2f(h));
  }
}

__global__ __launch_bounds__(256) void scan1_k(const int* __restrict__ icnt,
                                               int* __restrict__ psum, int M) {
  int base = blockIdx.x * 1024 + threadIdx.x * 4;
  int s = 0;
#pragma unroll
  for (int j = 0; j < 4; j++) {
    int i = base + j;
    if (i < M) s += icnt[i];
  }
  __shared__ int tmp[256];
  tmp[threadIdx.x] = s;
  __syncthreads();
  for (int off = 128; off > 0; off >>= 1) {
    if (threadIdx.x < off) tmp[threadIdx.x] += tmp[threadIdx.x + off];
    __syncthreads();
  }
  if (threadIdx.x == 0) psum[blockIdx.x] = tmp[0];
}

__global__ __launch_bounds__(256) void scan2_k(int* __restrict__ psum, int P) {
  __shared__ int tmp[256];
  __shared__ int carry_s;
  if (threadIdx.x == 0) carry_s = 0;
  __syncthreads();
  for (int base = 0; base < P; base += 256) {
    int i = base + threadIdx.x;
    int v = (i < P) ? psum[i] : 0;
    tmp[threadIdx.x] = v;
    __syncthreads();
    for (int off = 1; off < 256; off <<= 1) {
      int u = (threadIdx.x >= off) ? tmp[threadIdx.x - off] : 0;
      __syncthreads();
      tmp[threadIdx.x] += u;
      __syncthreads();
    }
    int carry = carry_s;
    if (i < P) psum[i] = carry + tmp[threadIdx.x] - v;
    __syncthreads();
    if (threadIdx.x == 0) carry_s = carry + tmp[255];
    __syncthreads();
  }
}

__global__ __launch_bounds__(256) void scan3_k(const int* __restrict__ icnt,
                                               const int* __restrict__ psum,
                                               int* __restrict__ offs, int M) {
  int base = blockIdx.x * 1024 + threadIdx.x * 4;
  int v[4];
  int s = 0;
#pragma unroll
  for (int j = 0; j < 4; j++) {
    int i = base + j;
    v[j] = (i < M) ? icnt[i] : 0;
    s += v[j];
  }
  __shared__ int tmp[256];
  tmp[threadIdx.x] = s;
  __syncthreads();
  for (int off = 1; off < 256; off <<= 1) {
    int u = (threadIdx.x >= off) ? tmp[threadIdx.x - off] : 0;
    __syncthreads();
    tmp[threadIdx.x] += u;
    __syncthreads();
  }
  int run = psum[blockIdx.x] + tmp[threadIdx.x] - s;
#pragma unroll
  for (int j = 0; j < 4; j++) {
    int i = base + j;
    if (i < M) {
      offs[i] = run;
      run += v[j];
    }
  }
}

__global__ __launch_bounds__(256) void scatter_k(const int* __restrict__ src,
                                                 const int* __restrict__ dst,
                                                 const int* __restrict__ et,
                                                 int* __restrict__ cursor,
                                                 int* __restrict__ csr, int E, int N) {
  int e = blockIdx.x * 256 + threadIdx.x;
  if (e >= E) return;
  int p = atomicAdd(&cursor[et[e] * N + dst[e]], 1);
  csr[p] = src[e];
}

// ====== layer-1 fused: batched-burst gather + split-bf16 MFMA -> h1 hi/lo ======
__global__ __launch_bounds__(256) void l1fused_k(
    const short* __restrict__ xh, const short* __restrict__ xl,
    const int* __restrict__ offs, const int* __restrict__ icnt, const int* __restrict__ csr,
    const short* __restrict__ wth, const short* __restrict__ wtl,
    const float* __restrict__ bias, short* __restrict__ h1h, short* __restrict__ h1l, int N) {
  const int t = threadIdx.x;
  const int lane = t & 63, w = t >> 6;
  const int m_ = lane & 15, q = lane >> 4;
  const int n0 = blockIdx.x * 64 + w * 16;
  int n = n0 + m_;
  if (n >= N) n = N - 1;

  short8_t ah0 = *(const short8_t*)&xh[(size_t)n * EMB + q * 8];
  short8_t al0 = *(const short8_t*)&xl[(size_t)n * EMB + q * 8];

  int beg[NREL], len[NREL];
#pragma unroll
  for (int r = 0; r < NREL; r++) {
    int idx = r * N + n;
    beg[r] = offs[idx];
    len[r] = icnt[idx];
  }
  // level-2: first 4 neighbor indices per relation (contiguous; csr padded +4)
  int id[NREL][4];
#pragma unroll
  for (int r = 0; r < NREL; r++)
#pragma unroll
    for (int j = 0; j < 4; j++) id[r][j] = csr[beg[r] + j];
  // level-3: 12 predicated row-slice loads, all independent
  short8_t tr[NREL][4];
#pragma unroll
  for (int r = 0; r < NREL; r++)
#pragma unroll
    for (int j = 0; j < 4; j++) {
      tr[r][j] = (short8_t){0, 0, 0, 0, 0, 0, 0, 0};
      if (j < len[r]) tr[r][j] = *(const short8_t*)&xh[(size_t)id[r][j] * EMB + q * 8];
    }
  float a[NREL][8];
#pragma unroll
  for (int r = 0; r < NREL; r++) {
#pragma unroll
    for (int i = 0; i < 8; i++) a[r][i] = 0.f;
#pragma unroll
    for (int j = 0; j < 4; j++)
#pragma unroll
      for (int i = 0; i < 8; i++) a[r][i] += bf2f(tr[r][j][i]);
  }
  // rare tail (len > 4)
  int mx = max(max(len[0], len[1]), len[2]);
  for (int j = 4; j < mx; j++) {
#pragma unroll
    for (int r = 0; r < NREL; r++)
      if (j < len[r]) {
        short8_t v = *(const short8_t*)&xh[(size_t)csr[beg[r] + j] * EMB + q * 8];
#pragma unroll
        for (int i = 0; i < 8; i++) a[r][i] += bf2f(v[i]);
      }
  }
  short8_t ahn[NREL], aln[NREL];
#pragma unroll
  for (int r = 0; r < NREL; r++) {
    float inv = 1.f / fmaxf((float)len[r], 1.f);
#pragma unroll
    for (int i = 0; i < 8; i++) a[r][i] *= inv;
    split8(a[r], &ahn[r], &aln[r]);
  }

  f32x4 acc[4];
#pragma unroll
  for (int i = 0; i < 4; i++) acc[i] = (f32x4){0.f, 0.f, 0.f, 0.f};
#pragma unroll
  for (int tt = 0; tt < 4; tt++) {
    const size_t wrow = (size_t)(16 * tt + m_) * 128;
#pragma unroll
    for (int g = 0; g < 4; g++) {
      short8_t bh = *(const short8_t*)&wth[wrow + g * 32 + q * 8];
      short8_t bl = *(const short8_t*)&wtl[wrow + g * 32 + q * 8];
      short8_t ah = (g == 0) ? ah0 : ahn[g - 1];
      short8_t al = (g == 0) ? al0 : aln[g - 1];
      acc[tt] = __builtin_amdgcn_mfma_f32_16x16x32_bf16(ah, bh, acc[tt], 0, 0, 0);
      acc[tt] = __builtin_amdgcn_mfma_f32_16x16x32_bf16(ah, bl, acc[tt], 0, 0, 0);
      acc[tt] = __builtin_amdgcn_mfma_f32_16x16x32_bf16(al, bh, acc[tt], 0, 0, 0);
    }
  }
#pragma unroll
  for (int tt = 0; tt < 4; tt++) {
    float bia = bias[16 * tt + m_];
#pragma unroll
    for (int reg = 0; reg < 4; reg++) {
      int node = n0 + q * 4 + reg;
      if (node < N) {
        float val = fmaxf(acc[tt][reg] + bia, 0.f);
        short hh = f2bf(val);
        h1h[(size_t)node * HID + 16 * tt + m_] = hh;
        h1l[(size_t)node * HID + 16 * tt + m_] = f2bf(val - bf2f(hh));
      }
    }
  }
}

// ====== layer-2 fused: batched-burst gather + split-bf16 MFMA + pooled epilogue ======
__global__ __launch_bounds__(256) void l2fused_k(
    const short* __restrict__ h1h, const short* __restrict__ h1l,
    const int* __restrict__ offs, const int* __restrict__ icnt, const int* __restrict__ csr,
    const short* __restrict__ wth, const short* __restrict__ wtl,
    const float* __restrict__ bias, const float* __restrict__ linW,
    const int* __restrict__ batch, float* __restrict__ gs, float* __restrict__ gc, int N) {
  const int t = threadIdx.x;
  const int lane = t & 63, w = t >> 6;
  const int m_ = lane & 15, q = lane >> 4;
  const int n0 = blockIdx.x * 64 + w * 16;
  int n = n0 + m_;
  if (n >= N) n = N - 1;

  f32x4 acc[4];
#pragma unroll
  for (int i = 0; i < 4; i++) acc[i] = (f32x4){0.f, 0.f, 0.f, 0.f};

  // ---- self segment ----
  {
    short8_t ah[2], al[2];
#pragma unroll
    for (int s_ = 0; s_ < 2; s_++) {
      ah[s_] = *(const short8_t*)&h1h[(size_t)n * HID + s_ * 32 + q * 8];
      al[s_] = *(const short8_t*)&h1l[(size_t)n * HID + s_ * 32 + q * 8];
    }
#pragma unroll
    for (int tt = 0; tt < 4; tt++) {
      const size_t wrow = (size_t)(16 * tt + m_) * 256;
#pragma unroll
      for (int s_ = 0; s_ < 2; s_++) {
        short8_t bh = *(const short8_t*)&wth[wrow + s_ * 32 + q * 8];
        short8_t bl = *(const short8_t*)&wtl[wrow + s_ * 32 + q * 8];
        acc[tt] = __builtin_amdgcn_mfma_f32_16x16x32_bf16(ah[s_], bh, acc[tt], 0, 0, 0);
        acc[tt] = __builtin_amdgcn_mfma_f32_16x16x32_bf16(ah[s_], bl, acc[tt], 0, 0, 0);
        acc[tt] = __builtin_amdgcn_mfma_f32_16x16x32_bf16(al[s_], bh, acc[tt], 0, 0, 0);
      }
    }
  }
  // ---- batched-burst neighbor gather on hi plane ----
  {
    int beg[NREL], len[NREL];
#pragma unroll
    for (int r = 0; r < NREL; r++) {
      int idx = r * N + n;
      beg[r] = offs[idx];
      len[r] = icnt[idx];
    }
    int id[NREL][4];
#pragma unroll
    for (int r = 0; r < NREL; r++)
#pragma unroll
      for (int j = 0; j < 4; j++) id[r][j] = csr[beg[r] + j];
    float a[NREL][2][8];
#pragma unroll
    for (int r = 0; r < NREL; r++)
#pragma unroll
      for (int s_ = 0; s_ < 2; s_++)
#pragma unroll
        for (int i = 0; i < 8; i++) a[r][s_][i] = 0.f;
    // two half-passes: 12 independent loads each
#pragma unroll
    for (int s_ = 0; s_ < 2; s_++) {
      short8_t tr[NREL][4];
#pragma unroll
      for (int r = 0; r < NREL; r++)
#pragma unroll
        for (int j = 0; j < 4; j++) {
          tr[r][j] = (short8_t){0, 0, 0, 0, 0, 0, 0, 0};
          if (j < len[r])
            tr[r][j] = *(const short8_t*)&h1h[(size_t)id[r][j] * HID + s_ * 32 + q * 8];
        }
#pragma unroll
      for (int r = 0; r < NREL; r++)
#pragma unroll
        for (int j = 0; j < 4; j++)
#pragma unroll
          for (int i = 0; i < 8; i++) a[r][s_][i] += bf2f(tr[r][j][i]);
    }
    // rare tail
    int mx = max(max(len[0], len[1]), len[2]);
    for (int j = 4; j < mx; j++) {
#pragma unroll
      for (int r = 0; r < NREL; r++)
        if (j < len[r]) {
          const short* p = &h1h[(size_t)csr[beg[r] + j] * HID];
#pragma unroll
          for (int s_ = 0; s_ < 2; s_++) {
            short8_t v = *(const short8_t*)&p[s_ * 32 + q * 8];
#pragma unroll
            for (int i = 0; i < 8; i++) a[r][s_][i] += bf2f(v[i]);
          }
        }
    }
#pragma unroll
    for (int r = 0; r < NREL; r++) {
      float inv = 1.f / fmaxf((float)len[r], 1.f);
      short8_t ah[2], al[2];
#pragma unroll
      for (int s_ = 0; s_ < 2; s_++) {
#pragma unroll
        for (int i = 0; i < 8; i++) a[r][s_][i] *= inv;
        split8(a[r][s_], &ah[s_], &al[s_]);
      }
#pragma unroll
      for (int tt = 0; tt < 4; tt++) {
        const size_t wrow = (size_t)(16 * tt + m_) * 256;
#pragma unroll
        for (int s_ = 0; s_ < 2; s_++) {
          short8_t bh = *(const short8_t*)&wth[wrow + (1 + r) * 64 + s_ * 32 + q * 8];
          short8_t bl = *(const short8_t*)&wtl[wrow + (1 + r) * 64 + s_ * 32 + q * 8];
          acc[tt] = __builtin_amdgcn_mfma_f32_16x16x32_bf16(ah[s_], bh, acc[tt], 0, 0, 0);
          acc[tt] = __builtin_amdgcn_mfma_f32_16x16x32_bf16(ah[s_], bl, acc[tt], 0, 0, 0);
          acc[tt] = __builtin_amdgcn_mfma_f32_16x16x32_bf16(al[s_], bh, acc[tt], 0, 0, 0);
        }
      }
    }
  }
  // pooled epilogue
  float bia[4], lw0[4], lw1[4];
#pragma unroll
  for (int tt = 0; tt < 4; tt++) {
    int col = 16 * tt + m_;
    bia[tt] = bias[col];
    lw0[tt] = linW[col * 2 + 0];
    lw1[tt] = linW[col * 2 + 1];
  }
#pragma unroll
  for (int reg = 0; reg < 4; reg++) {
    int node = n0 + q * 4 + reg;
    float p0 = 0.f, p1 = 0.f;
#pragma unroll
    for (int tt = 0; tt < 4; tt++) {
      float v = fmaxf(acc[tt][reg] + bia[tt], 0.f);
      p0 += v * lw0[tt];
      p1 += v * lw1[tt];
    }
#pragma unroll
    for (int o = 1; o < 16; o <<= 1) {
      p0 += __shfl_xor(p0, o, 64);
      p1 += __shfl_xor(p1, o, 64);
    }
    if (m_ == 0 && node < N) {
      int g = batch[node];
      atomicAdd(&gs[g * 2 + 0], p0);
      atomicAdd(&gs[g * 2 + 1], p1);
      atomicAdd(&gc[g], 1.0f);
    }
  }
}

__global__ __launch_bounds__(256) void final_k(const float* __restrict__ gs,
                                               const float* __restrict__ gc,
                                               const float* __restrict__ linb,
                                               float* __restrict__ out, int G) {
  int i = blockIdx.x * 256 + threadIdx.x;
  if (i >= G * 2) return;
  int g = i >> 1, o = i & 1;
  out[i] = gs[i] / fmaxf(gc[g], 1.0f) + linb[o];
}

extern "C" void kernel_launch(void* const* d_in, const int* in_sizes, int n_in,
                              void* d_out, int out_size, void* d_ws, size_t ws_size,
                              hipStream_t stream) {
  const int* sid = (const int*)d_in[0];
  const int* cid = (const int*)d_in[1];
  const int* pid = (const int*)d_in[2];
  const int* ei = (const int*)d_in[3];
  const int* et = (const int*)d_in[4];
  const int* batch = (const int*)d_in[5];
  const float* se = (const float*)d_in[7];
  const float* ce = (const float*)d_in[8];
  const float* pe = (const float*)d_in[9];
  const float* W1 = (const float*)d_in[10];
  const float* root1 = (const float*)d_in[11];
  const float* b1 = (const float*)d_in[12];
  const float* W2 = (const float*)d_in[13];
  const float* root2 = (const float*)d_in[14];
  const float* b2 = (const float*)d_in[15];
  const float* linW = (const float*)d_in[16];
  const float* linb = (const float*)d_in[17];
  float* out = (float*)d_out;

  const int N = in_sizes[0];
  const int E = in_sizes[4];
  const int G = out_size / 2;
  const int* src = ei;
  const int* dst = ei + E;
  const int M = N * NREL;
  const int P = (M + 1023) / 1024;

  // ---- workspace layout (strictly budgeted; 16B-aligned blocks) ----
  char* w = (char*)d_ws;
  short* h1h = (short*)w;  w += (size_t)N * HID * sizeof(short);
  short* h1l = (short*)w;  w += (size_t)N * HID * sizeof(short);
  short* xh = (short*)w;   w += (size_t)N * EMB * sizeof(short);
  short* xl = (short*)w;   w += (size_t)N * EMB * sizeof(short);
  float* gs = (float*)w;   w += (size_t)G * 2 * sizeof(float);
  float* gc = (float*)w;   w += (size_t)G * sizeof(float);
  int* icnt = (int*)w;     w += (size_t)M * sizeof(int);
  int* offs = (int*)w;     w += (size_t)M * sizeof(int);
  int* cursor = (int*)w;   w += (size_t)M * sizeof(int);
  int* csr = (int*)w;      w += ((size_t)E + 4) * sizeof(int);  // +4 pad for burst reads
  short* w1h = (short*)w;  w += (size_t)64 * 128 * sizeof(short);
  short* w1l = (short*)w;  w += (size_t)64 * 128 * sizeof(short);
  short* w2h = (short*)w;  w += (size_t)64 * 256 * sizeof(short);
  short* w2l = (short*)w;  w += (size_t)64 * 256 * sizeof(short);
  int* psum = (int*)w;     w += (size_t)P * sizeof(int);
  if ((size_t)(w - (char*)d_ws) > ws_size) return;  // fail loudly, no OOB

  hipMemsetAsync(icnt, 0, (size_t)M * sizeof(int), stream);
  hipMemsetAsync(gs, 0, (size_t)G * 3 * sizeof(float), stream);

  int prep_n = N * 8;  // covers E (1.5M) and weight ranges too for this problem size
  if (prep_n < E) prep_n = E;
  if (prep_n < 64 * 256) prep_n = 64 * 256;
  prep_k<<<(prep_n + 255) / 256, 256, 0, stream>>>(sid, cid, pid, se, ce, pe, xh, xl, dst, et,
                                                   icnt, root1, W1, root2, W2, w1h, w1l, w2h,
                                                   w2l, N, E);
  scan1_k<<<P, 256, 0, stream>>>(icnt, psum, M);
  scan2_k<<<1, 256, 0, stream>>>(psum, P);
  scan3_k<<<P, 256, 0, stream>>>(icnt, psum, offs, M);
  hipMemcpyAsync(cursor, offs, (size_t)M * sizeof(int), hipMemcpyDeviceToDevice, stream);
  scatter_k<<<(E + 255) / 256, 256, 0, stream>>>(src, dst, et, cursor, csr, E, N);

  int blocks = (N + 63) / 64;
  l1fused_k<<<blocks, 256, 0, stream>>>(xh, xl, offs, icnt, csr, w1h, w1l, b1, h1h, h1l, N);
  l2fused_k<<<blocks, 256, 0, stream>>>(h1h, h1l, offs, icnt, csr, w2h, w2l, b2, linW, batch,
                                        gs, gc, N);
  final_k<<<(G * 2 + 255) / 256, 256, 0, stream>>>(gs, gc, linb, out, G);
}